// Round 1
// baseline (620.678 us; speedup 1.0000x reference)
//
#include <hip/hip_runtime.h>

// ---------- types / helpers ----------
typedef __attribute__((ext_vector_type(4))) float f32x4;
typedef __attribute__((ext_vector_type(8))) __bf16 bf16x8;

__device__ __forceinline__ unsigned short f2b(float f) {
  unsigned int u = __builtin_bit_cast(unsigned int, f);
  u = (u + 0x7fffu + ((u >> 16) & 1u)) >> 16;
  return (unsigned short)u;
}
__device__ __forceinline__ float b2f(unsigned short h) {
  unsigned int u = ((unsigned int)h) << 16;
  return __builtin_bit_cast(float, u);
}
__device__ __forceinline__ __bf16 u2bf(unsigned short h) {
  return __builtin_bit_cast(__bf16, h);
}
__device__ __forceinline__ void gl_lds16(const void* g, void* l) {
  __builtin_amdgcn_global_load_lds(
      (const __attribute__((address_space(1))) void*)g,
      (__attribute__((address_space(3))) void*)l, 16, 0, 0);
}

// ---------- fp32 -> bf16 cast ----------
__global__ void cast_kernel(const float* __restrict__ src,
                            unsigned short* __restrict__ dst, int n4) {
  int i = blockIdx.x * blockDim.x + threadIdx.x;
  if (i >= n4) return;
  float4 v = ((const float4*)src)[i];
  ushort4 o;
  o.x = f2b(v.x); o.y = f2b(v.y); o.z = f2b(v.z); o.w = f2b(v.w);
  ((ushort4*)dst)[i] = o;
}

// ---------- RoPE cos/sin table: tab[l*64+i] ----------
__global__ void rope_table_kernel(float2* __restrict__ tab) {
  int idx = blockIdx.x * blockDim.x + threadIdx.x;  // 2048*64 = 131072
  int l = idx >> 6, i = idx & 63;
  float freq = powf(10000.0f, -(float)(2 * i) / 128.0f);
  float th = (float)l * freq;
  tab[idx] = make_float2(cosf(th), sinf(th));
}

// ---------- RoPE apply (z=0: q in-place; z=1: k in-place + fp32 out; z=2: v fp32 out) ----------
__global__ void rope_apply_kernel(unsigned short* __restrict__ qb,
                                  unsigned short* __restrict__ kb,
                                  unsigned short* __restrict__ vb,
                                  float* __restrict__ kout,
                                  float* __restrict__ vout,
                                  const float2* __restrict__ tab) {
  int z = blockIdx.y;
  int p = blockIdx.x * blockDim.x + threadIdx.x;  // 2*2048*16*64 pairs
  int i = p & 63;
  int t = p >> 6;
  int h = t & 15; t >>= 4;
  int l = t & 2047;
  int b = t >> 11;
  int base = ((b * 2048 + l) * 2048) + h * 128 + 2 * i;      // (B,L,D) layout
  int obase = ((b * 16 + h) * 2048 + l) * 128 + 2 * i;       // (B,H,L,Dh) layout
  if (z == 2) {
    vout[obase] = b2f(vb[base]);
    vout[obase + 1] = b2f(vb[base + 1]);
  } else {
    unsigned short* buf = z ? kb : qb;
    float x1 = b2f(buf[base]), x2 = b2f(buf[base + 1]);
    float2 cs = tab[l * 64 + i];
    float r1 = x1 * cs.x - x2 * cs.y;
    float r2 = x1 * cs.y + x2 * cs.x;
    buf[base] = f2b(r1);
    buf[base + 1] = f2b(r2);
    if (z == 1) { kout[obase] = r1; kout[obase + 1] = r2; }
  }
}

// ---------- NT GEMM: C[4096x2048] = A[4096x2048] * W[2048x2048]^T (bf16 in, bf16/f32 out) ----------
template <int OUT_F32>
__global__ __launch_bounds__(256) void gemm_nt(const unsigned short* __restrict__ A,
                                               const unsigned short* __restrict__ W,
                                               void* __restrict__ C) {
  __shared__ unsigned short As[128 * 32];
  __shared__ unsigned short Bs[128 * 32];
  const int K = 2048, N = 2048;
  int tid = threadIdx.x;
  int lane = tid & 63, wid = tid >> 6;
  int wr = wid >> 1, wc = wid & 1;
  int ln = lane & 15, kg = lane >> 4;
  int m0 = blockIdx.y * 128, n0 = blockIdx.x * 128;

  f32x4 acc[4][4] = {};

  int e0 = tid * 8;               // element index within 2048-elem staging chunk
  int r0 = e0 >> 5, c0 = e0 & 31; // tile row / k-col
  const unsigned short* Ag0 = A + (m0 + r0) * K + c0;
  const unsigned short* Ag1 = A + (m0 + 64 + r0) * K + c0;
  const unsigned short* Wg0 = W + (n0 + r0) * K + c0;
  const unsigned short* Wg1 = W + (n0 + 64 + r0) * K + c0;
  unsigned short* As0 = &As[e0];
  unsigned short* As1 = &As[2048 + e0];
  unsigned short* Bs0 = &Bs[e0];
  unsigned short* Bs1 = &Bs[2048 + e0];

  for (int kt = 0; kt < K; kt += 32) {
    gl_lds16(Ag0 + kt, As0);
    gl_lds16(Ag1 + kt, As1);
    gl_lds16(Wg0 + kt, Bs0);
    gl_lds16(Wg1 + kt, Bs1);
    __syncthreads();
    bf16x8 a[4], bfr[4];
#pragma unroll
    for (int m = 0; m < 4; ++m)
      a[m] = *(const bf16x8*)&As[(wr * 64 + m * 16 + ln) * 32 + kg * 8];
#pragma unroll
    for (int n = 0; n < 4; ++n)
      bfr[n] = *(const bf16x8*)&Bs[(wc * 64 + n * 16 + ln) * 32 + kg * 8];
#pragma unroll
    for (int m = 0; m < 4; ++m)
#pragma unroll
      for (int n = 0; n < 4; ++n)
        acc[m][n] = __builtin_amdgcn_mfma_f32_16x16x32_bf16(a[m], bfr[n], acc[m][n], 0, 0, 0);
    __syncthreads();
  }

  int row0 = m0 + wr * 64, col0 = n0 + wc * 64;
#pragma unroll
  for (int m = 0; m < 4; ++m)
#pragma unroll
    for (int n = 0; n < 4; ++n)
#pragma unroll
      for (int j = 0; j < 4; ++j) {
        int r = row0 + m * 16 + kg * 4 + j;
        int c = col0 + n * 16 + ln;
        float v = acc[m][n][j];
        if (OUT_F32)
          ((float*)C)[r * N + c] = v;
        else
          ((unsigned short*)C)[r * N + c] = f2b(v);
      }
}

// ---------- flash attention: 1 wave / 16 q-rows, KVBLK=32, causal ----------
__global__ __launch_bounds__(64) void attn_kernel(const unsigned short* __restrict__ Qb,
                                                  const unsigned short* __restrict__ Kb,
                                                  const unsigned short* __restrict__ Vb,
                                                  unsigned short* __restrict__ Ob) {
  __shared__ unsigned short p_lds[16 * 32];
  int lane = threadIdx.x;
  int ln = lane & 15, kg = lane >> 4;
  int qt = blockIdx.x, h = blockIdx.y, b = blockIdx.z;
  int q0 = qt * 16;
  const int D = 2048;
  const int bh = b * 2048 * 2048 + h * 128;  // (b, l=0, h*128) in (B,L,D)

  bf16x8 aq[4];
#pragma unroll
  for (int kc = 0; kc < 4; ++kc)
    aq[kc] = *(const bf16x8*)&Qb[bh + (q0 + ln) * D + kc * 32 + kg * 8];

  f32x4 o[8] = {};
  float m[4] = {-1e30f, -1e30f, -1e30f, -1e30f};
  float lsum[4] = {0.f, 0.f, 0.f, 0.f};
  const float scale = 0.08838834764831845f;  // 1/sqrt(128)

  int ktmax = (q0 + 15) >> 5;
  for (int kt = 0; kt <= ktmax; ++kt) {
    int kv0 = kt * 32;
    f32x4 s[2] = {};
#pragma unroll
    for (int n = 0; n < 2; ++n)
#pragma unroll
      for (int kc = 0; kc < 4; ++kc) {
        bf16x8 bk = *(const bf16x8*)&Kb[bh + (kv0 + n * 16 + ln) * D + kc * 32 + kg * 8];
        s[n] = __builtin_amdgcn_mfma_f32_16x16x32_bf16(aq[kc], bk, s[n], 0, 0, 0);
      }
    float alpha[4];
#pragma unroll
    for (int j = 0; j < 4; ++j) {
      int row = q0 + kg * 4 + j;
      float s0 = (kv0 + ln <= row) ? s[0][j] * scale : -1e30f;
      float s1 = (kv0 + 16 + ln <= row) ? s[1][j] * scale : -1e30f;
      s[0][j] = s0;
      s[1][j] = s1;
      float mx = fmaxf(s0, s1);
#pragma unroll
      for (int d = 1; d < 16; d <<= 1) mx = fmaxf(mx, __shfl_xor(mx, d));
      float mnew = fmaxf(m[j], mx);
      alpha[j] = __expf(m[j] - mnew);
      m[j] = mnew;
      float p0 = __expf(s0 - mnew);
      float p1 = __expf(s1 - mnew);
      s[0][j] = p0;
      s[1][j] = p1;
      float r = p0 + p1;
#pragma unroll
      for (int d = 1; d < 16; d <<= 1) r += __shfl_xor(r, d);
      lsum[j] = lsum[j] * alpha[j] + r;
    }
#pragma unroll
    for (int dt = 0; dt < 8; ++dt)
#pragma unroll
      for (int j = 0; j < 4; ++j) o[dt][j] *= alpha[j];
    // P -> LDS (C-layout) then re-read as A-operand layout
#pragma unroll
    for (int j = 0; j < 4; ++j) {
      p_lds[(kg * 4 + j) * 32 + ln] = f2b(s[0][j]);
      p_lds[(kg * 4 + j) * 32 + 16 + ln] = f2b(s[1][j]);
    }
    __syncthreads();
    bf16x8 ap = *(const bf16x8*)&p_lds[ln * 32 + kg * 8];
#pragma unroll
    for (int dt = 0; dt < 8; ++dt) {
      bf16x8 bv;
#pragma unroll
      for (int e = 0; e < 8; ++e)
        bv[e] = u2bf(Vb[bh + (kv0 + kg * 8 + e) * D + dt * 16 + ln]);
      o[dt] = __builtin_amdgcn_mfma_f32_16x16x32_bf16(ap, bv, o[dt], 0, 0, 0);
    }
    __syncthreads();
  }

  float inv[4];
#pragma unroll
  for (int j = 0; j < 4; ++j) inv[j] = 1.0f / lsum[j];
#pragma unroll
  for (int dt = 0; dt < 8; ++dt)
#pragma unroll
    for (int j = 0; j < 4; ++j) {
      float v = o[dt][j] * inv[j];
      Ob[bh + (q0 + kg * 4 + j) * D + dt * 16 + ln] = f2b(v);
    }
}

// ---------- launch ----------
extern "C" void kernel_launch(void* const* d_in, const int* in_sizes, int n_in,
                              void* d_out, int out_size, void* d_ws, size_t ws_size,
                              hipStream_t stream) {
  const float* x  = (const float*)d_in[0];
  // d_in[1] = mask: exactly the causal mask; applied analytically in attn_kernel.
  const float* Wq = (const float*)d_in[2];
  const float* Wk = (const float*)d_in[3];
  const float* Wv = (const float*)d_in[4];
  const float* Wo = (const float*)d_in[5];

  char* ws = (char*)d_ws;
  unsigned short* xb  = (unsigned short*)(ws + 0);          // 4096x2048 bf16 (16.8MB), reused as Ob
  unsigned short* wqb = (unsigned short*)(ws + 16777216);   // 2048x2048 bf16 (8.4MB each)
  unsigned short* wkb = (unsigned short*)(ws + 25165824);
  unsigned short* wvb = (unsigned short*)(ws + 33554432);
  unsigned short* wob = (unsigned short*)(ws + 41943040);
  unsigned short* qb  = (unsigned short*)(ws + 50331648);   // 4096x2048 bf16
  unsigned short* kb  = (unsigned short*)(ws + 67108864);
  unsigned short* vb  = (unsigned short*)(ws + 83886080);
  float2* tab         = (float2*)(ws + 100663296);          // 2048x64 cos/sin (1MB)
  unsigned short* ob  = xb;

  float* out  = (float*)d_out;           // (B,L,D) fp32
  float* kout = out + 8388608;           // (B,H,L,Dh) fp32
  float* vout = out + 16777216;          // (B,H,L,Dh) fp32

  cast_kernel<<<8192, 256, 0, stream>>>(x, xb, 2097152);
  cast_kernel<<<4096, 256, 0, stream>>>(Wq, wqb, 1048576);
  cast_kernel<<<4096, 256, 0, stream>>>(Wk, wkb, 1048576);
  cast_kernel<<<4096, 256, 0, stream>>>(Wv, wvb, 1048576);
  cast_kernel<<<4096, 256, 0, stream>>>(Wo, wob, 1048576);
  rope_table_kernel<<<512, 256, 0, stream>>>(tab);

  dim3 gg(16, 32);  // N/128, M/128
  gemm_nt<0><<<gg, 256, 0, stream>>>(xb, wqb, qb);
  gemm_nt<0><<<gg, 256, 0, stream>>>(xb, wkb, kb);
  gemm_nt<0><<<gg, 256, 0, stream>>>(xb, wvb, vb);

  rope_apply_kernel<<<dim3(16384, 3), 256, 0, stream>>>(qb, kb, vb, kout, vout, tab);

  attn_kernel<<<dim3(128, 16, 2), 64, 0, stream>>>(qb, kb, vb, ob);

  gemm_nt<1><<<gg, 256, 0, stream>>>(ob, wob, out);
}

// Round 2
// 540.314 us; speedup vs baseline: 1.1487x; 1.1487x over previous
//
#include <hip/hip_runtime.h>

// ---------- types / helpers ----------
typedef __attribute__((ext_vector_type(4))) float f32x4;
typedef __attribute__((ext_vector_type(8))) __bf16 bf16x8;

__device__ __forceinline__ unsigned short f2b(float f) {
  unsigned int u = __builtin_bit_cast(unsigned int, f);
  u = (u + 0x7fffu + ((u >> 16) & 1u)) >> 16;
  return (unsigned short)u;
}
__device__ __forceinline__ float b2f(unsigned short h) {
  unsigned int u = ((unsigned int)h) << 16;
  return __builtin_bit_cast(float, u);
}
__device__ __forceinline__ void gl_lds16(const void* g, void* l) {
  __builtin_amdgcn_global_load_lds(
      (const __attribute__((address_space(1))) void*)g,
      (__attribute__((address_space(3))) void*)l, 16, 0, 0);
}

// ---------- fp32 -> bf16 cast ----------
__global__ void cast_kernel(const float* __restrict__ src,
                            unsigned short* __restrict__ dst, int n4) {
  int i = blockIdx.x * blockDim.x + threadIdx.x;
  if (i >= n4) return;
  float4 v = ((const float4*)src)[i];
  ushort4 o;
  o.x = f2b(v.x); o.y = f2b(v.y); o.z = f2b(v.z); o.w = f2b(v.w);
  ((ushort4*)dst)[i] = o;
}

// cast 4 equal-size weight matrices in one launch
__global__ void cast4_kernel(const float* __restrict__ s0, const float* __restrict__ s1,
                             const float* __restrict__ s2, const float* __restrict__ s3,
                             unsigned short* __restrict__ d0, unsigned short* __restrict__ d1,
                             unsigned short* __restrict__ d2, unsigned short* __restrict__ d3,
                             int n4) {
  int i = blockIdx.x * blockDim.x + threadIdx.x;
  if (i >= n4) return;
  const float* src = blockIdx.y == 0 ? s0 : blockIdx.y == 1 ? s1 : blockIdx.y == 2 ? s2 : s3;
  unsigned short* dst = blockIdx.y == 0 ? d0 : blockIdx.y == 1 ? d1 : blockIdx.y == 2 ? d2 : d3;
  float4 v = ((const float4*)src)[i];
  ushort4 o;
  o.x = f2b(v.x); o.y = f2b(v.y); o.z = f2b(v.z); o.w = f2b(v.w);
  ((ushort4*)dst)[i] = o;
}

// ---------- RoPE cos/sin table: tab[l*64+i] ----------
__global__ void rope_table_kernel(float2* __restrict__ tab) {
  int idx = blockIdx.x * blockDim.x + threadIdx.x;  // 2048*64
  int l = idx >> 6, i = idx & 63;
  float freq = powf(10000.0f, -(float)(2 * i) / 128.0f);
  float th = (float)l * freq;
  tab[idx] = make_float2(cosf(th), sinf(th));
}

// ---------- RoPE apply (z=0: q in-place; z=1: k in-place + fp32 out; z=2: v fp32 out) ----------
__global__ void rope_apply_kernel(unsigned short* __restrict__ qb,
                                  unsigned short* __restrict__ kb,
                                  unsigned short* __restrict__ vb,
                                  float* __restrict__ kout,
                                  float* __restrict__ vout,
                                  const float2* __restrict__ tab) {
  int z = blockIdx.y;
  int p = blockIdx.x * blockDim.x + threadIdx.x;
  int i = p & 63;
  int t = p >> 6;
  int h = t & 15; t >>= 4;
  int l = t & 2047;
  int b = t >> 11;
  int base = ((b * 2048 + l) * 2048) + h * 128 + 2 * i;      // (B,L,D)
  int obase = ((b * 16 + h) * 2048 + l) * 128 + 2 * i;       // (B,H,L,Dh)
  if (z == 2) {
    vout[obase] = b2f(vb[base]);
    vout[obase + 1] = b2f(vb[base + 1]);
  } else {
    unsigned short* buf = z ? kb : qb;
    float x1 = b2f(buf[base]), x2 = b2f(buf[base + 1]);
    float2 cs = tab[l * 64 + i];
    float r1 = x1 * cs.x - x2 * cs.y;
    float r2 = x1 * cs.y + x2 * cs.x;
    buf[base] = f2b(r1);
    buf[base + 1] = f2b(r2);
    if (z == 1) { kout[obase] = r1; kout[obase + 1] = r2; }
  }
}

// ---------- tiled transpose: vb (B,L,D) head-slice [L][Dh] -> vt (B,H,Dh,L) ----------
__global__ __launch_bounds__(256) void transpose_v_kernel(const unsigned short* __restrict__ vb,
                                                          unsigned short* __restrict__ vt) {
  __shared__ unsigned short t[32][33];
  int bz = blockIdx.z;             // bh 0..31
  int b = bz >> 4, h = bz & 15;
  int l0 = blockIdx.x * 32, d0 = blockIdx.y * 32;
  const unsigned short* src = vb + (size_t)b * 2048 * 2048 + h * 128;
  unsigned short* dst = vt + (size_t)bz * 128 * 2048;
  int tx = threadIdx.x & 31, ty = threadIdx.x >> 5;  // ty 0..7
#pragma unroll
  for (int i = 0; i < 4; ++i)
    t[ty + 8 * i][tx] = src[(size_t)(l0 + ty + 8 * i) * 2048 + d0 + tx];
  __syncthreads();
#pragma unroll
  for (int i = 0; i < 4; ++i)
    dst[(size_t)(d0 + ty + 8 * i) * 2048 + l0 + tx] = t[tx][ty + 8 * i];
}

// ---------- NT GEMM: C[4096x2048] = A[4096x2048] * W[2048x2048]^T ----------
template <int OUT_F32>
__global__ __launch_bounds__(256) void gemm_nt(const unsigned short* __restrict__ A,
                                               const unsigned short* __restrict__ W,
                                               void* __restrict__ C) {
  __shared__ unsigned short As[128 * 32];
  __shared__ unsigned short Bs[128 * 32];
  const int K = 2048, N = 2048;
  int tid = threadIdx.x;
  int lane = tid & 63, wid = tid >> 6;
  int wr = wid >> 1, wc = wid & 1;
  int ln = lane & 15, kg = lane >> 4;
  int m0 = blockIdx.y * 128, n0 = blockIdx.x * 128;

  f32x4 acc[4][4] = {};

  int e0 = tid * 8;
  int r0 = e0 >> 5, c0 = e0 & 31;
  const unsigned short* Ag0 = A + (m0 + r0) * K + c0;
  const unsigned short* Ag1 = A + (m0 + 64 + r0) * K + c0;
  const unsigned short* Wg0 = W + (n0 + r0) * K + c0;
  const unsigned short* Wg1 = W + (n0 + 64 + r0) * K + c0;
  unsigned short* As0 = &As[e0];
  unsigned short* As1 = &As[2048 + e0];
  unsigned short* Bs0 = &Bs[e0];
  unsigned short* Bs1 = &Bs[2048 + e0];

  for (int kt = 0; kt < K; kt += 32) {
    gl_lds16(Ag0 + kt, As0);
    gl_lds16(Ag1 + kt, As1);
    gl_lds16(Wg0 + kt, Bs0);
    gl_lds16(Wg1 + kt, Bs1);
    __syncthreads();
    bf16x8 a[4], bfr[4];
#pragma unroll
    for (int m = 0; m < 4; ++m)
      a[m] = *(const bf16x8*)&As[(wr * 64 + m * 16 + ln) * 32 + kg * 8];
#pragma unroll
    for (int n = 0; n < 4; ++n)
      bfr[n] = *(const bf16x8*)&Bs[(wc * 64 + n * 16 + ln) * 32 + kg * 8];
#pragma unroll
    for (int m = 0; m < 4; ++m)
#pragma unroll
      for (int n = 0; n < 4; ++n)
        acc[m][n] = __builtin_amdgcn_mfma_f32_16x16x32_bf16(a[m], bfr[n], acc[m][n], 0, 0, 0);
    __syncthreads();
  }

  int row0 = m0 + wr * 64, col0 = n0 + wc * 64;
#pragma unroll
  for (int m = 0; m < 4; ++m)
#pragma unroll
    for (int n = 0; n < 4; ++n)
#pragma unroll
      for (int j = 0; j < 4; ++j) {
        int r = row0 + m * 16 + kg * 4 + j;
        int c = col0 + n * 16 + ln;
        float v = acc[m][n][j];
        if (OUT_F32)
          ((float*)C)[r * N + c] = v;
        else
          ((unsigned short*)C)[r * N + c] = f2b(v);
      }
}

// ---------- flash attention v2: 2 waves/block, QBLK=32/wave, KVBLK=64, balanced q-tile pairs ----------
__global__ __launch_bounds__(128) void attn2_kernel(const unsigned short* __restrict__ Qb,
                                                    const unsigned short* __restrict__ Kb,
                                                    const unsigned short* __restrict__ Vt,
                                                    unsigned short* __restrict__ Ob) {
  __shared__ unsigned short p_lds[2][32 * 72];
  const int D = 2048, L = 2048;
  int tid = threadIdx.x;
  int lane = tid & 63, wid = tid >> 6;
  int ln = lane & 15, kg = lane >> 4;
  int h = blockIdx.y, b = blockIdx.z;
  int pair = blockIdx.x * 2 + wid;                       // 0..31
  const size_t bh = (size_t)b * L * D + h * 128;         // Q,K,Ob base in (B,L,D)
  const unsigned short* vt = Vt + ((size_t)(b * 16 + h) * 128) * L;  // [Dh][L]
  unsigned short* pw = &p_lds[wid][0];
  const float scale = 0.08838834764831845f;  // 1/sqrt(128)

  for (int half = 0; half < 2; ++half) {
    int qt = half ? (63 - pair) : pair;
    int q0 = qt * 32;

    bf16x8 aq[2][4];
#pragma unroll
    for (int m = 0; m < 2; ++m)
#pragma unroll
      for (int kc = 0; kc < 4; ++kc)
        aq[m][kc] = *(const bf16x8*)&Qb[bh + (size_t)(q0 + m * 16 + ln) * D + kc * 32 + kg * 8];

    f32x4 o[2][8] = {};
    float mr[2][4], ls[2][4];
#pragma unroll
    for (int m = 0; m < 2; ++m)
#pragma unroll
      for (int j = 0; j < 4; ++j) { mr[m][j] = -1e30f; ls[m][j] = 0.f; }

    int nt = ((q0 + 31) >> 6) + 1;
    for (int kt = 0; kt < nt; ++kt) {
      int kv0 = kt * 64;
      f32x4 s[2][4] = {};
#pragma unroll
      for (int n = 0; n < 4; ++n)
#pragma unroll
        for (int kc = 0; kc < 4; ++kc) {
          bf16x8 bk = *(const bf16x8*)&Kb[bh + (size_t)(kv0 + n * 16 + ln) * D + kc * 32 + kg * 8];
          s[0][n] = __builtin_amdgcn_mfma_f32_16x16x32_bf16(aq[0][kc], bk, s[0][n], 0, 0, 0);
          s[1][n] = __builtin_amdgcn_mfma_f32_16x16x32_bf16(aq[1][kc], bk, s[1][n], 0, 0, 0);
        }

      bool full = (kv0 + 63) <= q0;  // wave-uniform
#pragma unroll
      for (int m = 0; m < 2; ++m)
#pragma unroll
        for (int j = 0; j < 4; ++j) {
          int row = q0 + m * 16 + kg * 4 + j;
          float sc[4];
#pragma unroll
          for (int n = 0; n < 4; ++n) {
            float v = s[m][n][j] * scale;
            if (!full && (kv0 + n * 16 + ln > row)) v = -1e30f;
            sc[n] = v;
          }
          float mx = fmaxf(fmaxf(sc[0], sc[1]), fmaxf(sc[2], sc[3]));
#pragma unroll
          for (int d = 1; d < 16; d <<= 1) mx = fmaxf(mx, __shfl_xor(mx, d));
          float mnew = fmaxf(mr[m][j], mx);
          float alpha = __expf(mr[m][j] - mnew);
          mr[m][j] = mnew;
          float r = 0.f;
#pragma unroll
          for (int n = 0; n < 4; ++n) {
            float pv = __expf(sc[n] - mnew);
            r += pv;
            pw[(m * 16 + kg * 4 + j) * 72 + n * 16 + ln] = f2b(pv);
          }
#pragma unroll
          for (int d = 1; d < 16; d <<= 1) r += __shfl_xor(r, d);
          ls[m][j] = ls[m][j] * alpha + r;
#pragma unroll
          for (int dt = 0; dt < 8; ++dt) o[m][dt][j] *= alpha;
        }

      // PV: o[m] += P(32x64) * V(64x128)
#pragma unroll
      for (int kst = 0; kst < 2; ++kst) {
        bf16x8 ap0 = *(const bf16x8*)&pw[(0 * 16 + ln) * 72 + kst * 32 + kg * 8];
        bf16x8 ap1 = *(const bf16x8*)&pw[(1 * 16 + ln) * 72 + kst * 32 + kg * 8];
#pragma unroll
        for (int dt = 0; dt < 8; ++dt) {
          bf16x8 bv = *(const bf16x8*)&vt[(size_t)(dt * 16 + ln) * L + kv0 + kst * 32 + kg * 8];
          o[0][dt] = __builtin_amdgcn_mfma_f32_16x16x32_bf16(ap0, bv, o[0][dt], 0, 0, 0);
          o[1][dt] = __builtin_amdgcn_mfma_f32_16x16x32_bf16(ap1, bv, o[1][dt], 0, 0, 0);
        }
      }
    }

#pragma unroll
    for (int m = 0; m < 2; ++m)
#pragma unroll
      for (int j = 0; j < 4; ++j) {
        float inv = 1.0f / ls[m][j];
        int row = q0 + m * 16 + kg * 4 + j;
#pragma unroll
        for (int dt = 0; dt < 8; ++dt)
          Ob[bh + (size_t)row * D + dt * 16 + ln] = f2b(o[m][dt][j] * inv);
      }
  }
}

// ---------- launch ----------
extern "C" void kernel_launch(void* const* d_in, const int* in_sizes, int n_in,
                              void* d_out, int out_size, void* d_ws, size_t ws_size,
                              hipStream_t stream) {
  const float* x  = (const float*)d_in[0];
  // d_in[1] = mask (causal; applied analytically)
  const float* Wq = (const float*)d_in[2];
  const float* Wk = (const float*)d_in[3];
  const float* Wv = (const float*)d_in[4];
  const float* Wo = (const float*)d_in[5];

  char* ws = (char*)d_ws;
  unsigned short* xb  = (unsigned short*)(ws + 0);          // 4096x2048 bf16; reused as Ob
  unsigned short* wqb = (unsigned short*)(ws + 16777216);
  unsigned short* wkb = (unsigned short*)(ws + 25165824);
  unsigned short* wvb = (unsigned short*)(ws + 33554432);
  unsigned short* wob = (unsigned short*)(ws + 41943040);
  unsigned short* qb  = (unsigned short*)(ws + 50331648);
  unsigned short* kb  = (unsigned short*)(ws + 67108864);
  unsigned short* vb  = (unsigned short*)(ws + 83886080);
  float2* tab         = (float2*)(ws + 100663296);
  unsigned short* vt  = wqb;  // 16.8MB over dead wqb+wkb (free after K GEMM)
  unsigned short* ob  = xb;

  float* out  = (float*)d_out;
  float* kout = out + 8388608;
  float* vout = out + 16777216;

  cast_kernel<<<8192, 256, 0, stream>>>(x, xb, 2097152);
  cast4_kernel<<<dim3(4096, 4), 256, 0, stream>>>(Wq, Wk, Wv, Wo, wqb, wkb, wvb, wob, 1048576);
  rope_table_kernel<<<512, 256, 0, stream>>>(tab);

  dim3 gg(16, 32);
  gemm_nt<0><<<gg, 256, 0, stream>>>(xb, wqb, qb);
  gemm_nt<0><<<gg, 256, 0, stream>>>(xb, wkb, kb);
  gemm_nt<0><<<gg, 256, 0, stream>>>(xb, wvb, vb);

  // vt overwrites wqb/wkb — both dead after the Q/K GEMMs above
  transpose_v_kernel<<<dim3(64, 4, 32), 256, 0, stream>>>(vb, vt);

  rope_apply_kernel<<<dim3(16384, 3), 256, 0, stream>>>(qb, kb, vb, kout, vout, tab);

  attn2_kernel<<<dim3(16, 16, 2), 128, 0, stream>>>(qb, kb, vt, ob);

  gemm_nt<1><<<gg, 256, 0, stream>>>(ob, wob, out);
}

// Round 3
// 331.024 us; speedup vs baseline: 1.8750x; 1.6323x over previous
//
#include <hip/hip_runtime.h>

// ---------- types / helpers ----------
typedef __attribute__((ext_vector_type(4))) float f32x4;
typedef __attribute__((ext_vector_type(8))) __bf16 bf16x8;

__device__ __forceinline__ unsigned short f2b(float f) {
  unsigned int u = __builtin_bit_cast(unsigned int, f);
  u = (u + 0x7fffu + ((u >> 16) & 1u)) >> 16;
  return (unsigned short)u;
}
__device__ __forceinline__ float b2f(unsigned short h) {
  unsigned int u = ((unsigned int)h) << 16;
  return __builtin_bit_cast(float, u);
}
__device__ __forceinline__ void gl_lds16(const void* g, void* l) {
  __builtin_amdgcn_global_load_lds(
      (const __attribute__((address_space(1))) void*)g,
      (__attribute__((address_space(3))) void*)l, 16, 0, 0);
}

// ---------- fp32 -> bf16 cast ----------
__global__ void cast_kernel(const float* __restrict__ src,
                            unsigned short* __restrict__ dst, int n4) {
  int i = blockIdx.x * blockDim.x + threadIdx.x;
  if (i >= n4) return;
  float4 v = ((const float4*)src)[i];
  ushort4 o;
  o.x = f2b(v.x); o.y = f2b(v.y); o.z = f2b(v.z); o.w = f2b(v.w);
  ((ushort4*)dst)[i] = o;
}

__global__ void cast4_kernel(const float* __restrict__ s0, const float* __restrict__ s1,
                             const float* __restrict__ s2, const float* __restrict__ s3,
                             unsigned short* __restrict__ d0, unsigned short* __restrict__ d1,
                             unsigned short* __restrict__ d2, unsigned short* __restrict__ d3,
                             int n4) {
  int i = blockIdx.x * blockDim.x + threadIdx.x;
  if (i >= n4) return;
  const float* src = blockIdx.y == 0 ? s0 : blockIdx.y == 1 ? s1 : blockIdx.y == 2 ? s2 : s3;
  unsigned short* dst = blockIdx.y == 0 ? d0 : blockIdx.y == 1 ? d1 : blockIdx.y == 2 ? d2 : d3;
  float4 v = ((const float4*)src)[i];
  ushort4 o;
  o.x = f2b(v.x); o.y = f2b(v.y); o.z = f2b(v.z); o.w = f2b(v.w);
  ((ushort4*)dst)[i] = o;
}

// ---------- RoPE cos/sin table ----------
__global__ void rope_table_kernel(float2* __restrict__ tab) {
  int idx = blockIdx.x * blockDim.x + threadIdx.x;
  int l = idx >> 6, i = idx & 63;
  float freq = powf(10000.0f, -(float)(2 * i) / 128.0f);
  float th = (float)l * freq;
  tab[idx] = make_float2(cosf(th), sinf(th));
}

// ---------- RoPE apply; q additionally pre-scaled by 1/sqrt(Dh)*log2(e) ----------
__global__ void rope_apply_kernel(unsigned short* __restrict__ qb,
                                  unsigned short* __restrict__ kb,
                                  unsigned short* __restrict__ vb,
                                  float* __restrict__ kout,
                                  float* __restrict__ vout,
                                  const float2* __restrict__ tab) {
  const float QS = 0.12751743f;  // (1/sqrt(128)) * log2(e)
  int z = blockIdx.y;
  int p = blockIdx.x * blockDim.x + threadIdx.x;
  int i = p & 63;
  int t = p >> 6;
  int h = t & 15; t >>= 4;
  int l = t & 2047;
  int b = t >> 11;
  int base = ((b * 2048 + l) * 2048) + h * 128 + 2 * i;
  int obase = ((b * 16 + h) * 2048 + l) * 128 + 2 * i;
  if (z == 2) {
    vout[obase] = b2f(vb[base]);
    vout[obase + 1] = b2f(vb[base + 1]);
  } else {
    unsigned short* buf = z ? kb : qb;
    float x1 = b2f(buf[base]), x2 = b2f(buf[base + 1]);
    float2 cs = tab[l * 64 + i];
    float r1 = x1 * cs.x - x2 * cs.y;
    float r2 = x1 * cs.y + x2 * cs.x;
    if (z == 1) {
      buf[base] = f2b(r1);
      buf[base + 1] = f2b(r2);
      kout[obase] = r1; kout[obase + 1] = r2;
    } else {
      buf[base] = f2b(r1 * QS);
      buf[base + 1] = f2b(r2 * QS);
    }
  }
}

// ---------- tiled transpose: vb (B,L,D) head-slice -> vt (B,H,Dh,L) ----------
__global__ __launch_bounds__(256) void transpose_v_kernel(const unsigned short* __restrict__ vb,
                                                          unsigned short* __restrict__ vt) {
  __shared__ unsigned short t[32][33];
  int bz = blockIdx.z;
  int b = bz >> 4, h = bz & 15;
  int l0 = blockIdx.x * 32, d0 = blockIdx.y * 32;
  const unsigned short* src = vb + (size_t)b * 2048 * 2048 + h * 128;
  unsigned short* dst = vt + (size_t)bz * 128 * 2048;
  int tx = threadIdx.x & 31, ty = threadIdx.x >> 5;
#pragma unroll
  for (int i = 0; i < 4; ++i)
    t[ty + 8 * i][tx] = src[(size_t)(l0 + ty + 8 * i) * 2048 + d0 + tx];
  __syncthreads();
#pragma unroll
  for (int i = 0; i < 4; ++i)
    dst[(size_t)(d0 + ty + 8 * i) * 2048 + l0 + tx] = t[tx][ty + 8 * i];
}

// ---------- NT GEMM (m97 structure) ----------
template <int OUT_F32>
__global__ __launch_bounds__(256) void gemm_nt(const unsigned short* __restrict__ A,
                                               const unsigned short* __restrict__ W,
                                               void* __restrict__ C) {
  __shared__ unsigned short As[128 * 32];
  __shared__ unsigned short Bs[128 * 32];
  const int K = 2048, N = 2048;
  int tid = threadIdx.x;
  int lane = tid & 63, wid = tid >> 6;
  int wr = wid >> 1, wc = wid & 1;
  int ln = lane & 15, kg = lane >> 4;
  int m0 = blockIdx.y * 128, n0 = blockIdx.x * 128;

  f32x4 acc[4][4] = {};

  int e0 = tid * 8;
  int r0 = e0 >> 5, c0 = e0 & 31;
  const unsigned short* Ag0 = A + (m0 + r0) * K + c0;
  const unsigned short* Ag1 = A + (m0 + 64 + r0) * K + c0;
  const unsigned short* Wg0 = W + (n0 + r0) * K + c0;
  const unsigned short* Wg1 = W + (n0 + 64 + r0) * K + c0;
  unsigned short* As0 = &As[e0];
  unsigned short* As1 = &As[2048 + e0];
  unsigned short* Bs0 = &Bs[e0];
  unsigned short* Bs1 = &Bs[2048 + e0];

  for (int kt = 0; kt < K; kt += 32) {
    gl_lds16(Ag0 + kt, As0);
    gl_lds16(Ag1 + kt, As1);
    gl_lds16(Wg0 + kt, Bs0);
    gl_lds16(Wg1 + kt, Bs1);
    __syncthreads();
    bf16x8 a[4], bfr[4];
#pragma unroll
    for (int m = 0; m < 4; ++m)
      a[m] = *(const bf16x8*)&As[(wr * 64 + m * 16 + ln) * 32 + kg * 8];
#pragma unroll
    for (int n = 0; n < 4; ++n)
      bfr[n] = *(const bf16x8*)&Bs[(wc * 64 + n * 16 + ln) * 32 + kg * 8];
#pragma unroll
    for (int m = 0; m < 4; ++m)
#pragma unroll
      for (int n = 0; n < 4; ++n)
        acc[m][n] = __builtin_amdgcn_mfma_f32_16x16x32_bf16(a[m], bfr[n], acc[m][n], 0, 0, 0);
    __syncthreads();
  }

  int row0 = m0 + wr * 64, col0 = n0 + wc * 64;
#pragma unroll
  for (int m = 0; m < 4; ++m)
#pragma unroll
    for (int n = 0; n < 4; ++n)
#pragma unroll
      for (int j = 0; j < 4; ++j) {
        int r = row0 + m * 16 + kg * 4 + j;
        int c = col0 + n * 16 + ln;
        float v = acc[m][n][j];
        if (OUT_F32)
          ((float*)C)[r * N + c] = v;
        else
          ((unsigned short*)C)[r * N + c] = f2b(v);
      }
}

// ---------- flash attention v3 ----------
// 4 waves/block, QBLK=32/wave (block = 128 q-rows), KVBLK=64.
// K/V staged in swizzled LDS (pre-swizzled global source), double-buffered.
// exp2 domain (Q pre-scaled), defer-max (THR=8), per-lane partial l-sum.
__global__ __launch_bounds__(256, 2) void attn3_kernel(const unsigned short* __restrict__ Qb,
                                                       const unsigned short* __restrict__ Kb,
                                                       const unsigned short* __restrict__ Vt,
                                                       unsigned short* __restrict__ Ob) {
  __shared__ unsigned short KS[2][8192];  // [64 kv][128 dh] swizzled, 16KB each
  __shared__ unsigned short VS[2][8192];  // [128 dh][64 kv] swizzled
  __shared__ unsigned short PS[4][2048];  // per-wave 32x64 swizzled
  const int D = 2048, L = 2048;
  int tid = threadIdx.x, lane = tid & 63, w = tid >> 6;
  int ln = lane & 15, kg = lane >> 4;
  int bid = blockIdx.x;
  int g = bid >> 5, bh = bid & 31;
  int qt = (g < 8) ? (15 - g) : (g - 8);  // paired so co-resident blocks sum to const work
  int b = bh >> 4, h = bh & 15;
  const size_t base = (size_t)b * L * D + h * 128;
  const unsigned short* Kp = Kb + base;
  const unsigned short* Qp = Qb + base;
  unsigned short* Op = Ob + base;
  const unsigned short* Vp = Vt + (size_t)bh * 128 * L;

  int q0 = qt * 128;
  int qw0 = q0 + w * 32;

  // Q fragments (already scaled by 1/sqrt(Dh)*log2e)
  bf16x8 aq[2][4];
#pragma unroll
  for (int m = 0; m < 2; ++m)
#pragma unroll
    for (int kc = 0; kc < 4; ++kc)
      aq[m][kc] = *(const bf16x8*)&Qp[(size_t)(qw0 + m * 16 + ln) * D + kc * 32 + kg * 8];

  f32x4 o[2][8] = {};
  float m2[2][4], ls[2][4];
#pragma unroll
  for (int m = 0; m < 2; ++m)
#pragma unroll
    for (int j = 0; j < 4; ++j) { m2[m][j] = -1e30f; ls[m][j] = 0.f; }

  // per-lane staging geometry (constant across tiles)
  int l16 = lane >> 4, l8 = lane >> 3, l7 = lane & 7;

#define STAGE(T, NB)                                                                   \
  {                                                                                    \
    int kv0_ = (T) << 6;                                                               \
    _Pragma("unroll") for (int i = 0; i < 4; ++i) {                                    \
      int cK = w * 4 + i;                                                              \
      int r = cK * 4 + l16;                                                            \
      int sw = ln ^ (r & 7);                                                           \
      gl_lds16(Kp + (size_t)(kv0_ + r) * D + sw * 8, &KS[NB][cK * 512 + lane * 8]);    \
      int dh = cK * 8 + l8;                                                            \
      int sv = l7 ^ (dh & 7);                                                          \
      gl_lds16(Vp + (size_t)dh * L + kv0_ + sv * 8, &VS[NB][cK * 512 + lane * 8]);     \
    }                                                                                  \
  }

  int nt = 2 * qt + 2;
  int mask_t = 2 * qt + (w >> 1);  // first tile needing mask for this wave; > mask_t => skip

  STAGE(0, 0);
  __syncthreads();

  for (int t = 0; t < nt; ++t) {
    int cur = t & 1;
    if (t + 1 < nt) STAGE(t + 1, cur ^ 1);

    if (t <= mask_t) {
      int kv0 = t << 6;
      // ---- QK^T ----
      f32x4 s[2][4] = {};
#pragma unroll
      for (int n = 0; n < 4; ++n)
#pragma unroll
        for (int kc = 0; kc < 4; ++kc) {
          bf16x8 bk = *(const bf16x8*)&KS[cur][(n * 16 + ln) * 128 + (((kc << 2) + kg) ^ (ln & 7)) * 8];
          s[0][n] = __builtin_amdgcn_mfma_f32_16x16x32_bf16(aq[0][kc], bk, s[0][n], 0, 0, 0);
          s[1][n] = __builtin_amdgcn_mfma_f32_16x16x32_bf16(aq[1][kc], bk, s[1][n], 0, 0, 0);
        }
      if (t == mask_t) {
#pragma unroll
        for (int m = 0; m < 2; ++m)
#pragma unroll
          for (int n = 0; n < 4; ++n)
#pragma unroll
            for (int j = 0; j < 4; ++j)
              if (kv0 + n * 16 + ln > qw0 + m * 16 + kg * 4 + j) s[m][n][j] = -1e30f;
      }
      // ---- softmax (log2 domain, defer-max) ----
      float pmax[2][4];
      bool near = true;
#pragma unroll
      for (int m = 0; m < 2; ++m)
#pragma unroll
        for (int j = 0; j < 4; ++j) {
          pmax[m][j] = fmaxf(fmaxf(s[m][0][j], s[m][1][j]), fmaxf(s[m][2][j], s[m][3][j]));
          near = near && (pmax[m][j] <= m2[m][j] + 8.0f);
        }
      if (!__all(near)) {
#pragma unroll
        for (int m = 0; m < 2; ++m)
#pragma unroll
          for (int j = 0; j < 4; ++j) {
            float mx = pmax[m][j];
#pragma unroll
            for (int d = 1; d < 16; d <<= 1) mx = fmaxf(mx, __shfl_xor(mx, d));
            mx = fmaxf(mx, m2[m][j]);
            float al = __builtin_amdgcn_exp2f(m2[m][j] - mx);
            m2[m][j] = mx;
            ls[m][j] *= al;
#pragma unroll
            for (int dt = 0; dt < 8; ++dt) o[m][dt][j] *= al;
          }
      }
#pragma unroll
      for (int m = 0; m < 2; ++m)
#pragma unroll
        for (int j = 0; j < 4; ++j) {
          int row = m * 16 + kg * 4 + j;
          float acc = 0.f;
#pragma unroll
          for (int n = 0; n < 4; ++n) {
            float p = __builtin_amdgcn_exp2f(s[m][n][j] - m2[m][j]);
            acc += p;
            unsigned int u = __builtin_bit_cast(unsigned int, p);
            PS[w][row * 64 + (((n * 2 + (ln >> 3)) ^ (row & 7)) * 8) + (ln & 7)] =
                (unsigned short)(u >> 16);
          }
          ls[m][j] += acc;
        }
      // ---- PV ----
#pragma unroll
      for (int kst = 0; kst < 2; ++kst) {
        bf16x8 ap0 = *(const bf16x8*)&PS[w][(ln) * 64 + (((kst << 2) + kg) ^ (ln & 7)) * 8];
        bf16x8 ap1 = *(const bf16x8*)&PS[w][(16 + ln) * 64 + (((kst << 2) + kg) ^ (ln & 7)) * 8];
#pragma unroll
        for (int dt = 0; dt < 8; ++dt) {
          bf16x8 bv = *(const bf16x8*)&VS[cur][(dt * 16 + ln) * 64 + (((kst << 2) + kg) ^ (ln & 7)) * 8];
          o[0][dt] = __builtin_amdgcn_mfma_f32_16x16x32_bf16(ap0, bv, o[0][dt], 0, 0, 0);
          o[1][dt] = __builtin_amdgcn_mfma_f32_16x16x32_bf16(ap1, bv, o[1][dt], 0, 0, 0);
        }
      }
    }
    __syncthreads();
  }
#undef STAGE

  // ---- finalize: reduce l across the 16 lanes sharing each row, store ----
#pragma unroll
  for (int m = 0; m < 2; ++m)
#pragma unroll
    for (int j = 0; j < 4; ++j) {
      float tsum = ls[m][j];
#pragma unroll
      for (int d = 1; d < 16; d <<= 1) tsum += __shfl_xor(tsum, d);
      float inv = 1.0f / tsum;
      int row = qw0 + m * 16 + kg * 4 + j;
#pragma unroll
      for (int dt = 0; dt < 8; ++dt)
        Op[(size_t)row * D + dt * 16 + ln] = f2b(o[m][dt][j] * inv);
    }
}

// ---------- launch ----------
extern "C" void kernel_launch(void* const* d_in, const int* in_sizes, int n_in,
                              void* d_out, int out_size, void* d_ws, size_t ws_size,
                              hipStream_t stream) {
  const float* x  = (const float*)d_in[0];
  // d_in[1] = mask (causal; applied analytically)
  const float* Wq = (const float*)d_in[2];
  const float* Wk = (const float*)d_in[3];
  const float* Wv = (const float*)d_in[4];
  const float* Wo = (const float*)d_in[5];

  char* ws = (char*)d_ws;
  unsigned short* xb  = (unsigned short*)(ws + 0);
  unsigned short* wqb = (unsigned short*)(ws + 16777216);
  unsigned short* wkb = (unsigned short*)(ws + 25165824);
  unsigned short* wvb = (unsigned short*)(ws + 33554432);
  unsigned short* wob = (unsigned short*)(ws + 41943040);
  unsigned short* qb  = (unsigned short*)(ws + 50331648);
  unsigned short* kb  = (unsigned short*)(ws + 67108864);
  unsigned short* vb  = (unsigned short*)(ws + 83886080);
  float2* tab         = (float2*)(ws + 100663296);
  unsigned short* vt  = wqb;  // reuse wqb+wkb after Q/K GEMMs
  unsigned short* ob  = xb;

  float* out  = (float*)d_out;
  float* kout = out + 8388608;
  float* vout = out + 16777216;

  cast_kernel<<<8192, 256, 0, stream>>>(x, xb, 2097152);
  cast4_kernel<<<dim3(4096, 4), 256, 0, stream>>>(Wq, Wk, Wv, Wo, wqb, wkb, wvb, wob, 1048576);
  rope_table_kernel<<<512, 256, 0, stream>>>(tab);

  dim3 gg(16, 32);
  gemm_nt<0><<<gg, 256, 0, stream>>>(xb, wqb, qb);
  gemm_nt<0><<<gg, 256, 0, stream>>>(xb, wkb, kb);
  gemm_nt<0><<<gg, 256, 0, stream>>>(xb, wvb, vb);

  transpose_v_kernel<<<dim3(64, 4, 32), 256, 0, stream>>>(vb, vt);

  rope_apply_kernel<<<dim3(16384, 3), 256, 0, stream>>>(qb, kb, vb, kout, vout, tab);

  attn3_kernel<<<512, 256, 0, stream>>>(qb, kb, vt, ob);

  gemm_nt<1><<<gg, 256, 0, stream>>>(ob, wob, out);
}